// Round 4
// baseline (546.234 us; speedup 1.0000x reference)
//
#include <hip/hip_runtime.h>
#include <math.h>

#define T_LEN   1024
#define D_DIM   512
#define B_DIM   16
#define OUT_T   1280
#define K_SEL   16
#define NCAND   20
#define NSER    (B_DIM * D_DIM)   /* 8192 series */

// d_ws layout:
//   [0, 16384)     double2 twd[1024]  e^{-2pi i m/1024} fp64 (cos, -sin)
//   [16384, 24576) float2  twf[1024]  e^{+2pi i m/1024} fp32 (cos, +sin)  [recon]
//   [24576, 32768) float2  twn[1024]  e^{-2pi i m/1024} fp32 (cos, -sin)  [dft]
//   [32768, +2MiB) float4  sel[8192][16]  (k, re*2/N, im*2/N, 0)
//
// d_out doubles as scratch for xT (16,512,1024) fp32 = 32 MB; fully
// overwritten by k_recon at the end.

// ---------------- kernel 0: twiddle tables ----------------
__global__ void k_tables(double2* __restrict__ twd, float2* __restrict__ twf,
                         float2* __restrict__ twn) {
    int m = blockIdx.x * blockDim.x + threadIdx.x;
    if (m >= T_LEN) return;
    const double w0 = 6.283185307179586476925286766559e0 / (double)T_LEN;
    double s, c;
    sincos(w0 * (double)m, &s, &c);
    twd[m] = make_double2(c, -s);               // e^{-i theta} fp64
    twf[m] = make_float2((float)c, (float)s);   // e^{+i theta} fp32
    twn[m] = make_float2((float)c, (float)-s);  // e^{-i theta} fp32
}

// ---------------- kernel T: transpose x(b,t,d) -> xT(b,d,t) ----------------
__global__ __launch_bounds__(256) void k_transpose(const float* __restrict__ x,
                                                   float* __restrict__ xT) {
    __shared__ float tile[32][33];
    int blk = blockIdx.x;            // b(16) * ttile(32) * dtile(16) = 8192
    int b  = blk >> 9;
    int tt = (blk >> 4) & 31;
    int dt = blk & 15;
    int t0 = tt * 32, d0 = dt * 32;
    int lr = threadIdx.x >> 5;       // 0..7
    int lc = threadIdx.x & 31;       // 0..31
    const float* xb = x + (size_t)b * T_LEN * D_DIM;
#pragma unroll
    for (int i = 0; i < 4; i++) {
        int row = lr + i * 8;
        tile[row][lc] = xb[(size_t)(t0 + row) * D_DIM + (d0 + lc)];
    }
    __syncthreads();
    float* xTb = xT + (size_t)b * D_DIM * T_LEN;
#pragma unroll
    for (int i = 0; i < 4; i++) {
        int row = lr + i * 8;        // d-row within tile
        xTb[(size_t)(d0 + row) * T_LEN + (t0 + lc)] = tile[lc][row];
    }
}

// ------- kernel 1: fp32 CT DFT + register top-20 + LDS fp64 refine -------
__global__ __launch_bounds__(256, 2) void k_dft_topk(const float* __restrict__ xT,
                                                     const double2* __restrict__ twd,
                                                     const float2* __restrict__ twn,
                                                     float4* __restrict__ sel) {
    int s    = blockIdx.x;           // series id = b*512 + d
    int tid  = threadIdx.x;
    int lane = tid & 63;
    int w    = tid >> 6;             // wave id 0..3

    __shared__ float xs[T_LEN];                       // 4 KB, live whole kernel
    __shared__ __align__(16) char smemA[16640];       // phase A: zs+twl; refine: twre+twim
    __shared__ float2 w32s[32];                       // e^{-2pi i m/32}
    __shared__ unsigned long long wcand[4 * NCAND];   // per-wave top-20 keys
    __shared__ int     candk[NCAND];
    __shared__ double2 candc[NCAND];

    float2* zs   = (float2*)smemA;              // [32][33]  z[k1][t0]
    float2* twl  = (float2*)(smemA + 8448);     // [1024]    e^{-2pi i m/1024} fp32
    double* twre = (double*)smemA;              // [1024]    (reuse after phase B)
    double* twim = (double*)(smemA + 8192);     // [1024]

    // ---- load series + tables (coalesced) ----
    const float* xp = xT + (size_t)s * T_LEN;
#pragma unroll
    for (int i = 0; i < 4; i++) xs[tid + 256 * i] = xp[tid + 256 * i];
#pragma unroll
    for (int i = 0; i < 4; i++) twl[tid + 256 * i] = twn[tid + 256 * i];
    if (tid < 32) w32s[tid] = twn[tid * 32];
    __syncthreads();

    // ---- phase A: y[k1][t0] = sum_t1 x[32 t1 + t0] W32^{k1 t1};  z = y*W1024^{k1 t0}
    {
        int k1  = tid & 31;
        int t0b = (tid >> 5) << 2;   // this thread owns t0b..t0b+3
        float yr0=0,yi0=0,yr1=0,yi1=0,yr2=0,yi2=0,yr3=0,yi3=0;
#pragma unroll
        for (int t1 = 0; t1 < 32; t1++) {
            const float4 xq = *(const float4*)&xs[32 * t1 + t0b];
            float2 wv = w32s[(k1 * t1) & 31];
            yr0 += xq.x * wv.x; yi0 += xq.x * wv.y;
            yr1 += xq.y * wv.x; yi1 += xq.y * wv.y;
            yr2 += xq.z * wv.x; yi2 += xq.z * wv.y;
            yr3 += xq.w * wv.x; yi3 += xq.w * wv.y;
        }
        float yrA[4] = {yr0, yr1, yr2, yr3};
        float yiA[4] = {yi0, yi1, yi2, yi3};
#pragma unroll
        for (int i = 0; i < 4; i++) {
            int t0 = t0b + i;
            float2 tw = twl[(k1 * t0) & (T_LEN - 1)];
            zs[k1 * 33 + t0] = make_float2(yrA[i] * tw.x - yiA[i] * tw.y,
                                           yrA[i] * tw.y + yiA[i] * tw.x);
        }
    }
    __syncthreads();

    // ---- phase B: c_k = sum_t0 z[k&31][t0] W32^{(k>>5) t0};  keys stay in REGISTERS
    unsigned long long keyA, keyB;
#pragma unroll
    for (int kk = 0; kk < 2; kk++) {
        int k   = tid + kk * 256;
        int kb1 = k & 31, k0 = k >> 5;
        float cr = 0.f, ci = 0.f;
#pragma unroll
        for (int t0 = 0; t0 < 32; t0++) {
            float2 z = zs[kb1 * 33 + t0];
            float2 wv = w32s[(k0 * t0) & 31];
            cr += z.x * wv.x - z.y * wv.y;
            ci += z.x * wv.y + z.y * wv.x;
        }
        float mag = cr * cr + ci * ci;
        unsigned long long key = (k == 0) ? 0ull
            : (((unsigned long long)__float_as_uint(mag) << 32)
               | (unsigned)(511 - k));
        if (kk == 0) keyA = key; else keyB = key;
    }

    // ---- wave-local top-20 (shuffle tournament; no barriers, no LDS) ----
    {
        unsigned long long mycand = 0ull;
        for (int r = 0; r < NCAND; r++) {
            unsigned long long best = keyA > keyB ? keyA : keyB;
#pragma unroll
            for (int off = 1; off <= 32; off <<= 1) {
                unsigned long long o = __shfl_xor(best, off);
                if (o > best) best = o;
            }
            if (lane == r) mycand = best;
            if (keyA == best) keyA = 0ull;
            else if (keyB == best) keyB = 0ull;
        }
        if (lane < NCAND) wcand[w * NCAND + lane] = mycand;
    }
    __syncthreads();   // phase B reads of zs/twl done; wcand visible

    // ---- stage fp64 twiddles into LDS (overlays zs/twl), split re/im ----
#pragma unroll
    for (int i = 0; i < 4; i++) {
        int m = tid + 256 * i;
        double2 t2 = twd[m];
        twre[m] = t2.x; twim[m] = t2.y;
    }

    // ---- wave 0: merge 4x20 -> global top-20 (shuffle tournament) ----
    if (w == 0) {
        unsigned long long a = wcand[lane];
        unsigned long long b = (lane < 16) ? wcand[64 + lane] : 0ull;
        for (int r = 0; r < NCAND; r++) {
            unsigned long long best = a > b ? a : b;
#pragma unroll
            for (int off = 1; off <= 32; off <<= 1) {
                unsigned long long o = __shfl_xor(best, off);
                if (o > best) best = o;
            }
            if (lane == 0) candk[r] = 511 - (int)(best & 0xffffffffull);
            if (a == best) a = 0ull;
            else if (b == best) b = 0ull;
        }
    }
    __syncthreads();   // candk + twre/twim ready

    // ---- fp64 refinement: exact 1024-term DFT per candidate (LDS twiddles) ----
#pragma unroll
    for (int j = 0; j < 5; j++) {
        int c = w * 5 + j;           // 4 waves x 5 = 20 candidates
        int k = candk[c];
        double cr = 0.0, ci = 0.0;
#pragma unroll
        for (int i = 0; i < 16; i++) {
            int t   = lane + (i << 6);
            int idx = (k * t) & (T_LEN - 1);
            double xv = (double)xs[t];
            cr = fma(xv, twre[idx], cr);
            ci = fma(xv, twim[idx], ci);
        }
#pragma unroll
        for (int off = 1; off <= 32; off <<= 1) {
            cr += __shfl_xor(cr, off);
            ci += __shfl_xor(ci, off);
        }
        if (lane == 0) candc[c] = make_double2(cr, ci);
    }
    __syncthreads();

    // ---- final: top-16 of 20 refined (fp64 mag, tie -> lower k), wave 0 ----
    if (tid < 64) {
        double m = -1.0; int k = 1 << 20; float re = 0.f, im = 0.f;
        if (tid < NCAND) {
            double2 d2 = candc[tid]; k = candk[tid];
            m = d2.x * d2.x + d2.y * d2.y;
            const double sc = 2.0 / (double)T_LEN;
            re = (float)(d2.x * sc); im = (float)(d2.y * sc);
        }
        for (int r = 0; r < K_SEL; r++) {
            double bm = m; int bk = k, bl = tid;
#pragma unroll
            for (int off = 1; off <= 32; off <<= 1) {
                double om = __shfl_xor(bm, off);
                int    ok = __shfl_xor(bk, off);
                int    ol = __shfl_xor(bl, off);
                if (om > bm || (om == bm && ok < bk)) { bm = om; bk = ok; bl = ol; }
            }
            float rre = __shfl(re, bl);
            float rim = __shfl(im, bl);
            if (tid == 0)
                sel[(size_t)s * K_SEL + r] = make_float4((float)bk, rre, rim, 0.f);
            if (tid == bl) m = -1.0;   // remove winner
        }
    }
}

// ---------------- kernel 2: sparse inverse reconstruction ----------------
__global__ __launch_bounds__(256) void k_recon(const float4* __restrict__ sel,
                                               const float2* __restrict__ twf,
                                               float* __restrict__ out) {
    int blk = blockIdx.x;            // b(16) * dblk(8) * tchunk(4) = 512
    int b    = blk >> 5;
    int dblk = (blk >> 2) & 7;
    int tc   = blk & 3;
    int tid  = threadIdx.x;
    int dd   = tid & 63;             // d within 64-wide tile
    int tg   = tid >> 6;             // 0..3 time-phase

    __shared__ float4 ssel[64][17];  // padded
    __shared__ float2 vt[T_LEN];     // V^m table, 8 KB

#pragma unroll
    for (int i = 0; i < 4; i++) vt[tid + 256 * i] = twf[tid + 256 * i];
    int d0 = dblk * 64;
#pragma unroll
    for (int i = 0; i < 4; i++) {
        int l = tid + 256 * i;       // 1024 entries = 64 series * 16
        int sdd = l >> 4, j = l & 15;
        ssel[sdd][j] = sel[((size_t)(b * D_DIM + d0 + sdd)) * K_SEL + j];
    }
    __syncthreads();

    int tstart = tc * 256 + tg;
    float zr[16], zi[16], sr[16], si[16];
#pragma unroll
    for (int j = 0; j < 16; j++) {
        float4 e = ssel[dd][j];
        int k = (int)e.x;
        float2 v0 = vt[(k * tstart) & (T_LEN - 1)];
        zr[j] = e.y * v0.x - e.z * v0.y;   // z = c * V^{k*tstart}
        zi[j] = e.y * v0.y + e.z * v0.x;
        float2 st = vt[(k * 4) & (T_LEN - 1)];
        sr[j] = st.x; si[j] = st.y;        // step V^{4k}
    }

    float* ob = out + (size_t)b * OUT_T * D_DIM + (d0 + dd);
    for (int it = 0; it < 64; it++) {
        int t = tstart + it * 4;
        float v = 0.0f;
#pragma unroll
        for (int j = 0; j < 16; j++) {
            v += zr[j];
            float nr = zr[j] * sr[j] - zi[j] * si[j];
            float ni = zr[j] * si[j] + zi[j] * sr[j];
            zr[j] = nr; zi[j] = ni;
        }
        ob[(size_t)t * D_DIM] = v;
        if (t < OUT_T - T_LEN)               // replicate t+1024 (periodicity)
            ob[(size_t)(t + T_LEN) * D_DIM] = v;
    }
}

// ---------------- launch ----------------
extern "C" void kernel_launch(void* const* d_in, const int* in_sizes, int n_in,
                              void* d_out, int out_size, void* d_ws, size_t ws_size,
                              hipStream_t stream) {
    (void)in_sizes; (void)n_in; (void)out_size; (void)ws_size;
    const float* x = (const float*)d_in[0];
    float* out = (float*)d_out;
    char* ws = (char*)d_ws;

    double2* twd = (double2*)ws;
    float2*  twf = (float2*)(ws + 16384);
    float2*  twn = (float2*)(ws + 24576);
    float4*  sel = (float4*)(ws + 32768);
    float*   xT  = out;   // reuse output buffer as transpose scratch (32MB < 40MB)

    hipLaunchKernelGGL(k_tables,    dim3(4),    dim3(256), 0, stream, twd, twf, twn);
    hipLaunchKernelGGL(k_transpose, dim3(8192), dim3(256), 0, stream, x, xT);
    hipLaunchKernelGGL(k_dft_topk,  dim3(8192), dim3(256), 0, stream, xT, twd, twn, sel);
    hipLaunchKernelGGL(k_recon,     dim3(512),  dim3(256), 0, stream, sel, twf, out);
}

// Round 6
// 220.416 us; speedup vs baseline: 2.4782x; 2.4782x over previous
//
#include <hip/hip_runtime.h>
#include <math.h>

#define T_LEN   1024
#define D_DIM   512
#define B_DIM   16
#define OUT_T   1280
#define K_SEL   16
#define TSEL    17        /* candidate rank target: 16 + 1 safety */
#define MAXC    64
#define NSER    (B_DIM * D_DIM)   /* 8192 series */

// d_ws layout:
//   [0, 16384)     double2 twd[1024]  e^{-2pi i m/1024} fp64 (cos, -sin)
//   [16384, 24576) float2  twf[1024]  e^{+2pi i m/1024} fp32 (cos, +sin)  [recon]
//   [24576, 32768) float2  twn[1024]  e^{-2pi i m/1024} fp32 (cos, -sin)  [dft]
//   [32768, +2MiB) float4  sel[8192][16]  (k, re*2/N, im*2/N, 0)
//
// d_out doubles as scratch for xT (16,512,1024) fp32 = 32 MB; fully
// overwritten by k_recon at the end.

// ---------------- kernel 0: twiddle tables ----------------
__global__ void k_tables(double2* __restrict__ twd, float2* __restrict__ twf,
                         float2* __restrict__ twn) {
    int m = blockIdx.x * blockDim.x + threadIdx.x;
    if (m >= T_LEN) return;
    const double w0 = 6.283185307179586476925286766559e0 / (double)T_LEN;
    double s, c;
    sincos(w0 * (double)m, &s, &c);
    twd[m] = make_double2(c, -s);               // e^{-i theta} fp64
    twf[m] = make_float2((float)c, (float)s);   // e^{+i theta} fp32
    twn[m] = make_float2((float)c, (float)-s);  // e^{-i theta} fp32
}

// ---------------- kernel T: transpose x(b,t,d) -> xT(b,d,t) ----------------
__global__ __launch_bounds__(256) void k_transpose(const float* __restrict__ x,
                                                   float* __restrict__ xT) {
    __shared__ float tile[32][33];
    int blk = blockIdx.x;            // b(16) * ttile(32) * dtile(16) = 8192
    int b  = blk >> 9;
    int tt = (blk >> 4) & 31;
    int dt = blk & 15;
    int t0 = tt * 32, d0 = dt * 32;
    int lr = threadIdx.x >> 5;       // 0..7
    int lc = threadIdx.x & 31;       // 0..31
    const float* xb = x + (size_t)b * T_LEN * D_DIM;
#pragma unroll
    for (int i = 0; i < 4; i++) {
        int row = lr + i * 8;
        tile[row][lc] = xb[(size_t)(t0 + row) * D_DIM + (d0 + lc)];
    }
    __syncthreads();
    float* xTb = xT + (size_t)b * D_DIM * T_LEN;
#pragma unroll
    for (int i = 0; i < 4; i++) {
        int row = lr + i * 8;        // d-row within tile
        xTb[(size_t)(d0 + row) * T_LEN + (t0 + lc)] = tile[lc][row];
    }
}

// ------- kernel 1: fp32 CT DFT + 2-level histogram cut + fp64 refine -------
// Selection: coarse 512-bucket histogram (bits>>22) locates the rank-17
// bucket B; a fine 1024-sub-bucket histogram (bits>>12 & 1023) inside B
// finds a sub-cut so candidates = {bucket>B} u {bucket==B & fine>=cut-1}.
// M ~ 17-19 (bounded), fully parallel, no tournaments, no fp64 LDS tables.
__global__ __launch_bounds__(256, 2) void k_dft_topk(const float* __restrict__ xT,
                                                     const double2* __restrict__ twd,
                                                     const float2* __restrict__ twn,
                                                     float4* __restrict__ sel) {
    int s    = blockIdx.x;           // series id = b*512 + d
    int tid  = threadIdx.x;
    int lane = tid & 63;
    int w    = tid >> 6;             // wave id 0..3

    __shared__ float   xs[T_LEN];                 // 4 KB, live whole kernel
    __shared__ __align__(16) char smemA[8448];    // zs (phase A/B) -> fineh (select)
    __shared__ float2  twl[T_LEN];                // 8 KB  e^{-2pi i m/1024} fp32
    __shared__ float2  w32s[32];                  // 256 B
    __shared__ int     hist[512];                 // 2 KB  coarse histogram
    __shared__ int     candk[MAXC];
    __shared__ double2 candc[MAXC];
    __shared__ int     Bsh, abovesh, fcsh, ncnt;

    float2* zs    = (float2*)smemA;   // [32][33] z[k1][t0] padded
    int*    fineh = (int*)smemA;      // [1024]   fine histogram (after phase B)

    // ---- load series + tables (coalesced) ----
    const float* xp = xT + (size_t)s * T_LEN;
#pragma unroll
    for (int i = 0; i < 4; i++) xs[tid + 256 * i] = xp[tid + 256 * i];
#pragma unroll
    for (int i = 0; i < 4; i++) twl[tid + 256 * i] = twn[tid + 256 * i];
    if (tid < 32) w32s[tid] = twn[tid * 32];
    hist[tid] = 0; hist[tid + 256] = 0;
    if (tid == 0) ncnt = 0;
    __syncthreads();

    // ---- phase A: y[k1][t0] = sum_t1 x[32 t1 + t0] W32^{k1 t1};  z = y*W1024^{k1 t0}
    {
        int k1  = tid & 31;
        int t0b = (tid >> 5) << 2;   // this thread owns t0b..t0b+3
        float yr0=0,yi0=0,yr1=0,yi1=0,yr2=0,yi2=0,yr3=0,yi3=0;
#pragma unroll
        for (int t1 = 0; t1 < 32; t1++) {
            const float4 xq = *(const float4*)&xs[32 * t1 + t0b];
            float2 wv = w32s[(k1 * t1) & 31];
            yr0 += xq.x * wv.x; yi0 += xq.x * wv.y;
            yr1 += xq.y * wv.x; yi1 += xq.y * wv.y;
            yr2 += xq.z * wv.x; yi2 += xq.z * wv.y;
            yr3 += xq.w * wv.x; yi3 += xq.w * wv.y;
        }
        float yrA[4] = {yr0, yr1, yr2, yr3};
        float yiA[4] = {yi0, yi1, yi2, yi3};
#pragma unroll
        for (int i = 0; i < 4; i++) {
            int t0 = t0b + i;
            float2 tw = twl[(k1 * t0) & (T_LEN - 1)];
            zs[k1 * 33 + t0] = make_float2(yrA[i] * tw.x - yiA[i] * tw.y,
                                           yrA[i] * tw.y + yiA[i] * tw.x);
        }
    }
    __syncthreads();

    // ---- phase B: c_k = sum_t0 z[k&31][t0] W32^{(k>>5) t0}; coarse histogram
    int bA = -1, bB = -1;            // coarse buckets of this thread's 2 bins
    int fA = 0,  fB = 0;             // fine sub-buckets
#pragma unroll
    for (int kk = 0; kk < 2; kk++) {
        int k   = tid + kk * 256;
        int kb1 = k & 31, k0 = k >> 5;
        float cr = 0.f, ci = 0.f;
#pragma unroll
        for (int t0 = 0; t0 < 32; t0++) {
            float2 z  = zs[kb1 * 33 + t0];
            float2 wv = w32s[(k0 * t0) & 31];
            cr += z.x * wv.x - z.y * wv.y;
            ci += z.x * wv.y + z.y * wv.x;
        }
        float mag = cr * cr + ci * ci;
        unsigned int bits = __float_as_uint(mag);
        if (k != 0) {
            int bc = (int)(bits >> 22);            // monotone coarse bucket
            int fc = (int)((bits >> 12) & 1023);   // monotone within coarse
            if (kk == 0) { bA = bc; fA = fc; } else { bB = bc; fB = fc; }
            atomicAdd(&hist[bc], 1);
        }
    }
    __syncthreads();   // S1: coarse hist done; zs dead -> reuse as fineh

    // ---- zero fine histogram (overlays zs) ----
#pragma unroll
    for (int i = 0; i < 4; i++) fineh[tid + 256 * i] = 0;

    // ---- wave 0: coarse suffix-scan; B = largest bucket with suffix >= TSEL
    if (tid < 64) {
        int c8[8]; int ssum = 0;
        int top = 511 - lane * 8;    // lane owns buckets top-7..top (descending)
#pragma unroll
        for (int j = 0; j < 8; j++) { c8[j] = hist[top - j]; ssum += c8[j]; }
        int inc = ssum;
#pragma unroll
        for (int off = 1; off < 64; off <<= 1) {
            int o = __shfl_up(inc, off);
            if (lane >= off) inc += o;
        }
        int P = inc - ssum;          // bins in buckets above this chunk
        if (P < TSEL && P + ssum >= TSEL) {     // exactly one lane
            int run = P;
#pragma unroll
            for (int j = 0; j < 8; j++) {
                run += c8[j];
                if (run >= TSEL) { Bsh = top - j; abovesh = run - c8[j]; break; }
            }
        }
    }
    __syncthreads();   // S2: fineh zeroed, Bsh/abovesh visible

    // ---- fine histogram over bins in bucket B ----
    int Bcut = Bsh;
    if (bA == Bcut) atomicAdd(&fineh[fA], 1);
    if (bB == Bcut) atomicAdd(&fineh[fB], 1);
    __syncthreads();   // S3: fineh complete

    // ---- wave 0: fine suffix-scan; sub-cut where above+suffix >= TSEL; -1 margin
    if (tid < 64) {
        int f16[16]; int ssum = 0;
        int ftop = 1023 - lane * 16;
#pragma unroll
        for (int j = 0; j < 16; j++) { f16[j] = fineh[ftop - j]; ssum += f16[j]; }
        int inc = ssum;
#pragma unroll
        for (int off = 1; off < 64; off <<= 1) {
            int o = __shfl_up(inc, off);
            if (lane >= off) inc += o;
        }
        int P   = inc - ssum;
        int tgt = TSEL - abovesh;    // >= 1
        if (P < tgt && P + ssum >= tgt) {       // exactly one lane
            int run = P;
#pragma unroll
            for (int j = 0; j < 16; j++) {
                run += f16[j];
                if (run >= tgt) {
                    int fc = ftop - j;
                    fcsh = fc > 0 ? fc - 1 : 0;   // 1-sub-bucket safety margin
                    break;
                }
            }
        }
    }
    __syncthreads();   // S4: fcsh visible

    // ---- gather candidates (order irrelevant) ----
    int fcm = fcsh;
    if (bA > Bcut || (bA == Bcut && fA >= fcm)) {
        int sl = atomicAdd(&ncnt, 1); if (sl < MAXC) candk[sl] = tid;
    }
    if (bB > Bcut || (bB == Bcut && fB >= fcm)) {
        int sl = atomicAdd(&ncnt, 1); if (sl < MAXC) candk[sl] = tid + 256;
    }
    __syncthreads();   // S5: candk/ncnt ready
    int M = ncnt < MAXC ? ncnt : MAXC;

    // ---- fp64 refinement: exact 1024-term DFT per candidate.
    //      Twiddles by 16-step rotation recurrence (start: twd[k*lane], step:
    //      wave-uniform twd[64k mod 1024]). No LDS tables -> no bank conflicts.
    for (int c = w; c < M; c += 4) {
        int k = candk[c];
        double2 st = twd[(k << 6) & (T_LEN - 1)];
        double2 w0 = twd[(k * lane) & (T_LEN - 1)];
        double wr = w0.x, wi = w0.y, cr = 0.0, ci = 0.0;
#pragma unroll
        for (int i = 0; i < 16; i++) {
            double xv = (double)xs[lane + (i << 6)];
            cr = fma(xv, wr, cr);
            ci = fma(xv, wi, ci);
            double nr = fma(wr, st.x, -wi * st.y);
            double ni = fma(wr, st.y,  wi * st.x);
            wr = nr; wi = ni;
        }
#pragma unroll
        for (int off = 1; off <= 32; off <<= 1) {
            cr += __shfl_xor(cr, off);
            ci += __shfl_xor(ci, off);
        }
        if (lane == 0) candc[c] = make_double2(cr, ci);
    }
    __syncthreads();   // S6: candc ready

    // ---- final: rank-count among M refined (fp64 mag, tie -> lower k).
    //      Lane with rank r < 16 writes slot r (= descending-mag order).
    if (tid < 64) {
        double m = -1.0; int k = 1 << 20; double sre = 0.0, sim = 0.0;
        if (lane < M) {
            double2 d2 = candc[lane]; k = candk[lane];
            m = d2.x * d2.x + d2.y * d2.y;
            sre = d2.x; sim = d2.y;
        }
        int rank = 0;
        for (int j = 0; j < M; j++) {
            double om = __shfl(m, j);
            int    ok = __shfl(k, j);
            rank += (om > m || (om == m && ok < k)) ? 1 : 0;
        }
        if (lane < M && rank < K_SEL) {
            const double sc = 2.0 / (double)T_LEN;
            sel[(size_t)s * K_SEL + rank] =
                make_float4((float)k, (float)(sre * sc), (float)(sim * sc), 0.f);
        }
    }
}

// ---------------- kernel 2: sparse inverse reconstruction ----------------
__global__ __launch_bounds__(256) void k_recon(const float4* __restrict__ sel,
                                               const float2* __restrict__ twf,
                                               float* __restrict__ out) {
    int blk = blockIdx.x;            // b(16) * dblk(8) * tchunk(4) = 512
    int b    = blk >> 5;
    int dblk = (blk >> 2) & 7;
    int tc   = blk & 3;
    int tid  = threadIdx.x;
    int dd   = tid & 63;             // d within 64-wide tile
    int tg   = tid >> 6;             // 0..3 time-phase

    __shared__ float4 ssel[64][17];  // padded
    __shared__ float2 vt[T_LEN];     // V^m table, 8 KB

#pragma unroll
    for (int i = 0; i < 4; i++) vt[tid + 256 * i] = twf[tid + 256 * i];
    int d0 = dblk * 64;
#pragma unroll
    for (int i = 0; i < 4; i++) {
        int l = tid + 256 * i;       // 1024 entries = 64 series * 16
        int sdd = l >> 4, j = l & 15;
        ssel[sdd][j] = sel[((size_t)(b * D_DIM + d0 + sdd)) * K_SEL + j];
    }
    __syncthreads();

    int tstart = tc * 256 + tg;
    float zr[16], zi[16], sr[16], si[16];
#pragma unroll
    for (int j = 0; j < 16; j++) {
        float4 e = ssel[dd][j];
        int k = (int)e.x;
        float2 v0 = vt[(k * tstart) & (T_LEN - 1)];
        zr[j] = e.y * v0.x - e.z * v0.y;   // z = c * V^{k*tstart}
        zi[j] = e.y * v0.y + e.z * v0.x;
        float2 st = vt[(k * 4) & (T_LEN - 1)];
        sr[j] = st.x; si[j] = st.y;        // step V^{4k}
    }

    float* ob = out + (size_t)b * OUT_T * D_DIM + (d0 + dd);
    for (int it = 0; it < 64; it++) {
        int t = tstart + it * 4;
        float v = 0.0f;
#pragma unroll
        for (int j = 0; j < 16; j++) {
            v += zr[j];
            float nr = zr[j] * sr[j] - zi[j] * si[j];
            float ni = zr[j] * si[j] + zi[j] * sr[j];
            zr[j] = nr; zi[j] = ni;
        }
        ob[(size_t)t * D_DIM] = v;
        if (t < OUT_T - T_LEN)               // replicate t+1024 (periodicity)
            ob[(size_t)(t + T_LEN) * D_DIM] = v;
    }
}

// ---------------- launch ----------------
extern "C" void kernel_launch(void* const* d_in, const int* in_sizes, int n_in,
                              void* d_out, int out_size, void* d_ws, size_t ws_size,
                              hipStream_t stream) {
    (void)in_sizes; (void)n_in; (void)out_size; (void)ws_size;
    const float* x = (const float*)d_in[0];
    float* out = (float*)d_out;
    char* ws = (char*)d_ws;

    double2* twd = (double2*)ws;
    float2*  twf = (float2*)(ws + 16384);
    float2*  twn = (float2*)(ws + 24576);
    float4*  sel = (float4*)(ws + 32768);
    float*   xT  = out;   // reuse output buffer as transpose scratch (32MB < 40MB)

    hipLaunchKernelGGL(k_tables,    dim3(4),    dim3(256), 0, stream, twd, twf, twn);
    hipLaunchKernelGGL(k_transpose, dim3(8192), dim3(256), 0, stream, x, xT);
    hipLaunchKernelGGL(k_dft_topk,  dim3(8192), dim3(256), 0, stream, xT, twd, twn, sel);
    hipLaunchKernelGGL(k_recon,     dim3(512),  dim3(256), 0, stream, sel, twf, out);
}

// Round 7
// 170.410 us; speedup vs baseline: 3.2054x; 1.2934x over previous
//
#include <hip/hip_runtime.h>
#include <math.h>

#define T_LEN   1024
#define D_DIM   512
#define B_DIM   16
#define OUT_T   1280
#define K_SEL   16
#define TSEL    17        /* candidate rank target: 16 + 1 safety */
#define MAXC    64
#define NSER    (B_DIM * D_DIM)   /* 8192 series */

// d_ws layout:
//   [0, 16384)     double2 twd[1024]  e^{-2pi i m/1024} fp64 (cos, -sin)
//   [16384, 24576) float2  twf[1024]  e^{+2pi i m/1024} fp32 (cos, +sin)  [recon]
//   [24576, 32768) float2  twn[1024]  e^{-2pi i m/1024} fp32 (cos, -sin)  [dft]
//   [32768, +2MiB) float4  sel[8192][16]  (k, re*2/N, im*2/N, 0)
//
// d_out doubles as scratch for xT (16,512,1024) fp32 = 32 MB; fully
// overwritten by k_recon at the end.

// ------- kernel T: transpose x(b,t,d)->xT(b,d,t); tail blocks build tables -------
__global__ __launch_bounds__(256) void k_transpose_tables(const float* __restrict__ x,
                                                          float* __restrict__ xT,
                                                          double2* __restrict__ twd,
                                                          float2* __restrict__ twf,
                                                          float2* __restrict__ twn) {
    __shared__ float tile[32][33];
    int blk = blockIdx.x;
    if (blk >= 8192) {               // 4 tail blocks: twiddle tables
        int m = (blk - 8192) * 256 + threadIdx.x;   // 0..1023
        const double w0 = 6.283185307179586476925286766559e0 / (double)T_LEN;
        double s, c;
        sincos(w0 * (double)m, &s, &c);
        twd[m] = make_double2(c, -s);               // e^{-i theta} fp64
        twf[m] = make_float2((float)c, (float)s);   // e^{+i theta} fp32
        twn[m] = make_float2((float)c, (float)-s);  // e^{-i theta} fp32
        return;
    }
    int b  = blk >> 9;               // b(16) * ttile(32) * dtile(16)
    int tt = (blk >> 4) & 31;
    int dt = blk & 15;
    int t0 = tt * 32, d0 = dt * 32;
    int lr = threadIdx.x >> 5;       // 0..7
    int lc = threadIdx.x & 31;       // 0..31
    const float* xb = x + (size_t)b * T_LEN * D_DIM;
#pragma unroll
    for (int i = 0; i < 4; i++) {
        int row = lr + i * 8;
        tile[row][lc] = xb[(size_t)(t0 + row) * D_DIM + (d0 + lc)];
    }
    __syncthreads();
    float* xTb = xT + (size_t)b * D_DIM * T_LEN;
#pragma unroll
    for (int i = 0; i < 4; i++) {
        int row = lr + i * 8;        // d-row within tile
        xTb[(size_t)(d0 + row) * T_LEN + (t0 + lc)] = tile[lc][row];
    }
}

// ------- kernel 1: fp32 CT DFT + 2-level histogram cut + CONDITIONAL fp64 refine -------
// Slot order is irrelevant (recon sums all 16), so ranks come from fp32 mags;
// fp64 refine runs only when the rank-15/16 mag^2 gap < 1e-4 rel (~0.5% of
// blocks; our-fp32-vs-numpy deviation ~2e-6 -> 50x margin).
__global__ __launch_bounds__(256, 2) void k_dft_topk(const float* __restrict__ xT,
                                                     const double2* __restrict__ twd,
                                                     const float2* __restrict__ twn,
                                                     float4* __restrict__ sel) {
    int s    = blockIdx.x;           // series id = b*512 + d
    int tid  = threadIdx.x;
    int lane = tid & 63;
    int w    = tid >> 6;             // wave id 0..3

    __shared__ float   xs[T_LEN];                 // 4 KB, live whole kernel
    __shared__ __align__(16) char smemA[8448];    // zs (phase A/B) -> fineh (select)
    __shared__ float2  twl[T_LEN];                // 8 KB  e^{-2pi i m/1024} fp32
    __shared__ float2  w32s[32];                  // 256 B
    __shared__ int     hist[512];                 // 2 KB  coarse histogram
    __shared__ int     candk[MAXC];
    __shared__ float2  candv[MAXC];               // fp32 (cr,ci) at gather
    __shared__ double2 candc[MAXC];               // fp64 refined (rare path)
    __shared__ int     Bsh, abovesh, fcsh, ncnt, needref;

    float2* zs    = (float2*)smemA;   // [32][33] z[k1][t0] padded
    int*    fineh = (int*)smemA;      // [1024]   fine histogram (after phase B)

    // ---- load series + tables (coalesced) ----
    const float* xp = xT + (size_t)s * T_LEN;
#pragma unroll
    for (int i = 0; i < 4; i++) xs[tid + 256 * i] = xp[tid + 256 * i];
#pragma unroll
    for (int i = 0; i < 4; i++) twl[tid + 256 * i] = twn[tid + 256 * i];
    if (tid < 32) w32s[tid] = twn[tid * 32];
    hist[tid] = 0; hist[tid + 256] = 0;
    if (tid == 0) ncnt = 0;
    __syncthreads();

    // ---- phase A: y[k1][t0] = sum_t1 x[32 t1 + t0] W32^{k1 t1};  z = y*W1024^{k1 t0}
    {
        int k1  = tid & 31;
        int t0b = (tid >> 5) << 2;   // this thread owns t0b..t0b+3
        float yr0=0,yi0=0,yr1=0,yi1=0,yr2=0,yi2=0,yr3=0,yi3=0;
#pragma unroll
        for (int t1 = 0; t1 < 32; t1++) {
            const float4 xq = *(const float4*)&xs[32 * t1 + t0b];
            float2 wv = w32s[(k1 * t1) & 31];
            yr0 += xq.x * wv.x; yi0 += xq.x * wv.y;
            yr1 += xq.y * wv.x; yi1 += xq.y * wv.y;
            yr2 += xq.z * wv.x; yi2 += xq.z * wv.y;
            yr3 += xq.w * wv.x; yi3 += xq.w * wv.y;
        }
        float yrA[4] = {yr0, yr1, yr2, yr3};
        float yiA[4] = {yi0, yi1, yi2, yi3};
#pragma unroll
        for (int i = 0; i < 4; i++) {
            int t0 = t0b + i;
            float2 tw = twl[(k1 * t0) & (T_LEN - 1)];
            zs[k1 * 33 + t0] = make_float2(yrA[i] * tw.x - yiA[i] * tw.y,
                                           yrA[i] * tw.y + yiA[i] * tw.x);
        }
    }
    __syncthreads();

    // ---- phase B: c_k = sum_t0 z[k&31][t0] W32^{(k>>5) t0}; keep values in regs
    float crr[2], cii[2];
    int   bb[2], ff[2];
#pragma unroll
    for (int kk = 0; kk < 2; kk++) {
        int k   = tid + kk * 256;
        int kb1 = k & 31, k0 = k >> 5;
        float cr = 0.f, ci = 0.f;
#pragma unroll
        for (int t0 = 0; t0 < 32; t0++) {
            float2 z  = zs[kb1 * 33 + t0];
            float2 wv = w32s[(k0 * t0) & 31];
            cr += z.x * wv.x - z.y * wv.y;
            ci += z.x * wv.y + z.y * wv.x;
        }
        crr[kk] = cr; cii[kk] = ci;
        if (k == 0) { bb[kk] = -1; ff[kk] = 0; }
        else {
            float mag = cr * cr + ci * ci;
            unsigned int bits = __float_as_uint(mag);
            bb[kk] = (int)(bits >> 22);            // monotone coarse bucket
            ff[kk] = (int)((bits >> 12) & 1023);   // monotone within coarse
            atomicAdd(&hist[bb[kk]], 1);
        }
    }
    __syncthreads();   // S1: coarse hist done; zs dead -> reuse as fineh

    // ---- zero fine histogram (overlays zs) ----
#pragma unroll
    for (int i = 0; i < 4; i++) fineh[tid + 256 * i] = 0;

    // ---- wave 0: coarse suffix-scan; B = largest bucket with suffix >= TSEL
    if (tid < 64) {
        int c8[8]; int ssum = 0;
        int top = 511 - lane * 8;    // lane owns buckets top-7..top (descending)
#pragma unroll
        for (int j = 0; j < 8; j++) { c8[j] = hist[top - j]; ssum += c8[j]; }
        int inc = ssum;
#pragma unroll
        for (int off = 1; off < 64; off <<= 1) {
            int o = __shfl_up(inc, off);
            if (lane >= off) inc += o;
        }
        int P = inc - ssum;          // bins in buckets above this chunk
        if (P < TSEL && P + ssum >= TSEL) {     // exactly one lane
            int run = P;
#pragma unroll
            for (int j = 0; j < 8; j++) {
                run += c8[j];
                if (run >= TSEL) { Bsh = top - j; abovesh = run - c8[j]; break; }
            }
        }
    }
    __syncthreads();   // S2: fineh zeroed, Bsh/abovesh visible

    // ---- fine histogram over bins in bucket B ----
    int Bcut = Bsh;
    if (bb[0] == Bcut) atomicAdd(&fineh[ff[0]], 1);
    if (bb[1] == Bcut) atomicAdd(&fineh[ff[1]], 1);
    __syncthreads();   // S3: fineh complete

    // ---- wave 0: fine suffix-scan; sub-cut where above+suffix >= TSEL; -1 margin
    if (tid < 64) {
        int f16[16]; int ssum = 0;
        int ftop = 1023 - lane * 16;
#pragma unroll
        for (int j = 0; j < 16; j++) { f16[j] = fineh[ftop - j]; ssum += f16[j]; }
        int inc = ssum;
#pragma unroll
        for (int off = 1; off < 64; off <<= 1) {
            int o = __shfl_up(inc, off);
            if (lane >= off) inc += o;
        }
        int P   = inc - ssum;
        int tgt = TSEL - abovesh;    // >= 1
        if (P < tgt && P + ssum >= tgt) {       // exactly one lane
            int run = P;
#pragma unroll
            for (int j = 0; j < 16; j++) {
                run += f16[j];
                if (run >= tgt) {
                    int fc = ftop - j;
                    fcsh = fc > 0 ? fc - 1 : 0;   // 1-sub-bucket safety margin
                    break;
                }
            }
        }
    }
    __syncthreads();   // S4: fcsh visible

    // ---- gather candidates with values (order irrelevant) ----
    int fcm = fcsh;
    if (bb[0] > Bcut || (bb[0] == Bcut && ff[0] >= fcm)) {
        int sl = atomicAdd(&ncnt, 1);
        if (sl < MAXC) { candk[sl] = tid; candv[sl] = make_float2(crr[0], cii[0]); }
    }
    if (bb[1] > Bcut || (bb[1] == Bcut && ff[1] >= fcm)) {
        int sl = atomicAdd(&ncnt, 1);
        if (sl < MAXC) { candk[sl] = tid + 256; candv[sl] = make_float2(crr[1], cii[1]); }
    }
    __syncthreads();   // S5: candk/candv/ncnt ready
    int M = ncnt < MAXC ? ncnt : MAXC;

    // ---- wave 0: fp32 rank-count + boundary-gap test ----
    int    rank32 = 64;
    float  myMag  = -1.f; int myK = 1 << 20; float2 myV = make_float2(0.f, 0.f);
    if (tid < 64) {
        bool act = lane < M;
        if (act) {
            myK = candk[lane]; myV = candv[lane];
            myMag = myV.x * myV.x + myV.y * myV.y;
        }
        rank32 = 0;
        for (int j = 0; j < M; j++) {
            float om = __shfl(myMag, j);
            int   ok = __shfl(myK, j);
            rank32 += (om > myMag || (om == myMag && ok < myK)) ? 1 : 0;
        }
        float a = (act && rank32 == 15) ? myMag : -1.f;   // 16th largest (mag^2)
        float b = (act && rank32 == 16) ? myMag : -1.f;   // 17th largest
#pragma unroll
        for (int off = 1; off <= 32; off <<= 1) {
            a = fmaxf(a, __shfl_xor(a, off));
            b = fmaxf(b, __shfl_xor(b, off));
        }
        if (lane == 0) needref = (a - b < a * 1e-4f) ? 1 : 0;
    }
    __syncthreads();   // S6: needref visible

    // ---- RARE: fp64 refinement of all M candidates (rotation recurrence) ----
    if (needref) {
        for (int c = w; c < M; c += 4) {
            int k = candk[c];
            double2 st = twd[(k << 6) & (T_LEN - 1)];
            double2 w0 = twd[(k * lane) & (T_LEN - 1)];
            double wr = w0.x, wi = w0.y, cr = 0.0, ci = 0.0;
#pragma unroll
            for (int i = 0; i < 16; i++) {
                double xv = (double)xs[lane + (i << 6)];
                cr = fma(xv, wr, cr);
                ci = fma(xv, wi, ci);
                double nr = fma(wr, st.x, -wi * st.y);
                double ni = fma(wr, st.y,  wi * st.x);
                wr = nr; wi = ni;
            }
#pragma unroll
            for (int off = 1; off <= 32; off <<= 1) {
                cr += __shfl_xor(cr, off);
                ci += __shfl_xor(ci, off);
            }
            if (lane == 0) candc[c] = make_double2(cr, ci);
        }
    }
    __syncthreads();   // S7: candc ready (if refined)

    // ---- final write: rank r < 16 -> slot r ----
    if (tid < 64) {
        if (!needref) {
            const float sc = 1.0f / 512.0f;    // 2/1024, exact
            if (lane < M && rank32 < K_SEL)
                sel[(size_t)s * K_SEL + rank32] =
                    make_float4((float)myK, myV.x * sc, myV.y * sc, 0.f);
        } else {
            double m = -1.0; int k = 1 << 20; double sre = 0.0, sim = 0.0;
            if (lane < M) {
                double2 d2 = candc[lane]; k = candk[lane];
                m = d2.x * d2.x + d2.y * d2.y;
                sre = d2.x; sim = d2.y;
            }
            int rank = 0;
            for (int j = 0; j < M; j++) {
                double om = __shfl(m, j);
                int    ok = __shfl(k, j);
                rank += (om > m || (om == m && ok < k)) ? 1 : 0;
            }
            if (lane < M && rank < K_SEL) {
                const double sc = 2.0 / (double)T_LEN;
                sel[(size_t)s * K_SEL + rank] =
                    make_float4((float)k, (float)(sre * sc), (float)(sim * sc), 0.f);
            }
        }
    }
}

// ---------------- kernel 2: sparse inverse reconstruction ----------------
__global__ __launch_bounds__(256) void k_recon(const float4* __restrict__ sel,
                                               const float2* __restrict__ twf,
                                               float* __restrict__ out) {
    int blk = blockIdx.x;            // b(16) * dblk(8) * tchunk(8) = 1024
    int b    = blk >> 6;
    int dblk = (blk >> 3) & 7;
    int tc   = blk & 7;
    int tid  = threadIdx.x;
    int dd   = tid & 63;             // d within 64-wide tile
    int tg   = tid >> 6;             // 0..3 time-phase

    __shared__ float4 ssel[64][17];  // padded
    __shared__ float2 vt[T_LEN];     // V^m table, 8 KB

#pragma unroll
    for (int i = 0; i < 4; i++) vt[tid + 256 * i] = twf[tid + 256 * i];
    int d0 = dblk * 64;
#pragma unroll
    for (int i = 0; i < 4; i++) {
        int l = tid + 256 * i;       // 1024 entries = 64 series * 16
        int sdd = l >> 4, j = l & 15;
        ssel[sdd][j] = sel[((size_t)(b * D_DIM + d0 + sdd)) * K_SEL + j];
    }
    __syncthreads();

    int tstart = tc * 128 + tg;
    float zr[16], zi[16], sr[16], si[16];
#pragma unroll
    for (int j = 0; j < 16; j++) {
        float4 e = ssel[dd][j];
        int k = (int)e.x;
        float2 v0 = vt[(k * tstart) & (T_LEN - 1)];
        zr[j] = e.y * v0.x - e.z * v0.y;   // z = c * V^{k*tstart}
        zi[j] = e.y * v0.y + e.z * v0.x;
        float2 st = vt[(k * 4) & (T_LEN - 1)];
        sr[j] = st.x; si[j] = st.y;        // step V^{4k}
    }

    float* ob = out + (size_t)b * OUT_T * D_DIM + (d0 + dd);
    for (int it = 0; it < 32; it++) {
        int t = tstart + it * 4;
        float v = 0.0f;
#pragma unroll
        for (int j = 0; j < 16; j++) {
            v += zr[j];
            float nr = zr[j] * sr[j] - zi[j] * si[j];
            float ni = zr[j] * si[j] + zi[j] * sr[j];
            zr[j] = nr; zi[j] = ni;
        }
        ob[(size_t)t * D_DIM] = v;
        if (t < OUT_T - T_LEN)               // replicate t+1024 (periodicity)
            ob[(size_t)(t + T_LEN) * D_DIM] = v;
    }
}

// ---------------- launch ----------------
extern "C" void kernel_launch(void* const* d_in, const int* in_sizes, int n_in,
                              void* d_out, int out_size, void* d_ws, size_t ws_size,
                              hipStream_t stream) {
    (void)in_sizes; (void)n_in; (void)out_size; (void)ws_size;
    const float* x = (const float*)d_in[0];
    float* out = (float*)d_out;
    char* ws = (char*)d_ws;

    double2* twd = (double2*)ws;
    float2*  twf = (float2*)(ws + 16384);
    float2*  twn = (float2*)(ws + 24576);
    float4*  sel = (float4*)(ws + 32768);
    float*   xT  = out;   // reuse output buffer as transpose scratch (32MB < 40MB)

    hipLaunchKernelGGL(k_transpose_tables, dim3(8196), dim3(256), 0, stream,
                       x, xT, twd, twf, twn);
    hipLaunchKernelGGL(k_dft_topk, dim3(8192), dim3(256), 0, stream, xT, twd, twn, sel);
    hipLaunchKernelGGL(k_recon,    dim3(1024), dim3(256), 0, stream, sel, twf, out);
}